// Round 8
// baseline (251.717 us; speedup 1.0000x reference)
//
#include <hip/hip_runtime.h>
#include <hip/hip_bf16.h>

typedef __bf16 bf16;
typedef __bf16 bf16x4 __attribute__((ext_vector_type(4)));
typedef __bf16 bf16x8 __attribute__((ext_vector_type(8)));
typedef float  f32x4  __attribute__((ext_vector_type(4)));

#define NEG_BIG (-1e30f)
#define LOG2E 1.44269504088896340736f

#define AS1(p) ((const __attribute__((address_space(1))) void*)(p))
#define AS3(p) ((__attribute__((address_space(3))) void*)(p))

// async global->LDS, 16B/lane; dest = wave-uniform base + lane*16 (m104/m108)
__device__ __forceinline__ void stage16(const void* g, void* lds_uniform_base) {
    __builtin_amdgcn_global_load_lds(AS1(g), AS3(lds_uniform_base), 16, 0, 0);
}

__device__ __forceinline__ bf16x8 cvt8(const float* __restrict__ p) {
    bf16x8 r;
#pragma unroll
    for (int i = 0; i < 8; ++i) r[i] = (bf16)p[i];
    return r;
}

// ---- DPP butterfly reduce over 16 consecutive lanes (pure VALU, no LDS) ----
template <int CTRL>
__device__ __forceinline__ float dpp_max_step(float x) {
    int v = __builtin_bit_cast(int, x);
    int s = __builtin_amdgcn_update_dpp(v, v, CTRL, 0xF, 0xF, true);
    return fmaxf(x, __builtin_bit_cast(float, s));
}
template <int CTRL>
__device__ __forceinline__ float dpp_add_step(float x) {
    int v = __builtin_bit_cast(int, x);
    int s = __builtin_amdgcn_update_dpp(v, v, CTRL, 0xF, 0xF, true);
    return x + __builtin_bit_cast(float, s);
}
__device__ __forceinline__ float red16_max(float x) {
    x = dpp_max_step<0xB1>(x);
    x = dpp_max_step<0x4E>(x);
    x = dpp_max_step<0x141>(x);
    x = dpp_max_step<0x140>(x);
    return x;
}
__device__ __forceinline__ float red16_sum(float x) {
    x = dpp_add_step<0xB1>(x);
    x = dpp_add_step<0x4E>(x);
    x = dpp_add_step<0x141>(x);
    x = dpp_add_step<0x140>(x);
    return x;
}

#if __has_builtin(__builtin_amdgcn_exp2f)
#define EXP2F(x) __builtin_amdgcn_exp2f(x)
#else
#define EXP2F(x) exp2f(x)
#endif

// ---------------------------------------------------------------------------
// f32->bf16: x -> xb (ws), Wq/Wk/Wv -> wb (d_out scratch). (R7-proven.)
// ---------------------------------------------------------------------------
__global__ __launch_bounds__(256) void conv_all(
    const float* __restrict__ x,  const float* __restrict__ wq,
    const float* __restrict__ wk, const float* __restrict__ wv,
    bf16* __restrict__ xb, bf16* __restrict__ wb)
{
    const int blk = blockIdx.x;
    const float* src; bf16* dst; size_t off;
    if (blk < 2048)      { src = x;  dst = xb;           off = (size_t)blk * 2048; }
    else if (blk < 2560) { src = wq; dst = wb;           off = (size_t)(blk - 2048) * 2048; }
    else if (blk < 3072) { src = wk; dst = wb + 1048576; off = (size_t)(blk - 2560) * 2048; }
    else                 { src = wv; dst = wb + 2097152; off = (size_t)(blk - 3072) * 2048; }
    const size_t i = off + (size_t)threadIdx.x * 8;
    *(bf16x8*)(dst + i) = cvt8(src + i);
}

// ---------------------------------------------------------------------------
// Fused QKV projection, all-bf16 (R7-proven core). y = xb @ Wb.T + b.
// Q is scaled by 0.125*log2e (exp2-domain softmax). V is written TRANSPOSED:
// V^T[bh][64][2048] so attn reads it directly as the PV B-operand.
// ---------------------------------------------------------------------------
__global__ __launch_bounds__(256) void qkv_gemm(
    const bf16* __restrict__ Xb, const bf16* __restrict__ Wb,
    const float* __restrict__ bq, const float* __restrict__ bk, const float* __restrict__ bv,
    bf16* __restrict__ qo, bf16* __restrict__ ko, bf16* __restrict__ vo)
{
    __shared__ alignas(16) bf16 As[128 * 32];
    __shared__ alignas(16) bf16 Bs[128 * 32];

    const int t    = threadIdx.x;
    const int lane = t & 63, w = t >> 6;
    const int quad = lane >> 4, col = lane & 15;
    const int nt = blockIdx.x;            // 0..23
    const int mt = blockIdx.y;            // 0..31
    const int region = nt >> 3;           // 0=q 1=k 2=v
    const int n0 = (nt & 7) * 128;
    const int m0 = mt * 128;
    const int K  = 1024;

    const bf16*  W    = Wb + (size_t)region * 1048576;
    const float* bias = region == 0 ? bq : (region == 1 ? bk : bv);

    const int wm = (w >> 1) * 64, wn = (w & 1) * 64;
    f32x4 acc[4][4] = {};

    for (int k0 = 0; k0 < K; k0 += 32) {
        __syncthreads();
#pragma unroll
        for (int i = 0; i < 2; ++i) {
            int c = i * 256 + t;
            stage16(Xb + (size_t)(m0 + (c >> 2)) * K + k0 + (c & 3) * 8,
                    As + (i * 256 + w * 64) * 8);
        }
#pragma unroll
        for (int i = 0; i < 2; ++i) {
            int c = i * 256 + t;
            stage16(W + (size_t)(n0 + (c >> 2)) * K + k0 + (c & 3) * 8,
                    Bs + (i * 256 + w * 64) * 8);
        }
        __syncthreads();

        bf16x8 a[4], b[4];
#pragma unroll
        for (int i = 0; i < 4; ++i)
            a[i] = *(const bf16x8*)(As + (wm + i * 16 + col) * 32 + quad * 8);
#pragma unroll
        for (int j = 0; j < 4; ++j)
            b[j] = *(const bf16x8*)(Bs + (wn + j * 16 + col) * 32 + quad * 8);
#pragma unroll
        for (int i = 0; i < 4; ++i)
#pragma unroll
            for (int j = 0; j < 4; ++j)
                acc[i][j] = __builtin_amdgcn_mfma_f32_16x16x32_bf16(a[i], b[j], acc[i][j], 0, 0, 0);
    }

    if (region == 2) {
        // V^T epilogue: rows d = n&63, cols s (contiguous in r) -> packed 8B stores
#pragma unroll
        for (int i = 0; i < 4; ++i) {
            const int mbase = m0 + wm + i * 16 + quad * 4;
            const int b_ = mbase >> 11, s = mbase & 2047;
#pragma unroll
            for (int j = 0; j < 4; ++j) {
                const int n = n0 + wn + j * 16 + col;
                const float bb = bias[n];
                const int h = n >> 6, d = n & 63;
                bf16x4 pk;
#pragma unroll
                for (int r = 0; r < 4; ++r) pk[r] = (bf16)(acc[i][j][r] + bb);
                *(bf16x4*)(vo + ((size_t)(b_ * 16 + h) * 64 + d) * 2048 + s) = pk;
            }
        }
    } else {
        bf16* out = region == 0 ? qo : ko;
        const float scale = region == 0 ? (0.125f * LOG2E) : 1.0f;
#pragma unroll
        for (int i = 0; i < 4; ++i) {
            const int mbase = m0 + wm + i * 16 + quad * 4;
#pragma unroll
            for (int j = 0; j < 4; ++j) {
                const int n = n0 + wn + j * 16 + col;
                const float bb = bias[n];
                const int h = n >> 6, d = n & 63;
#pragma unroll
                for (int r = 0; r < 4; ++r) {
                    const int m  = mbase + r;
                    const int b_ = m >> 11, s = m & 2047;
                    out[(((size_t)(b_ * 16 + h)) * 2048 + s) * 64 + d] =
                        (bf16)((acc[i][j][r] + bb) * scale);
                }
            }
        }
    }
}

// ---------------------------------------------------------------------------
// Flash attention — 64-row q-tiles, ALL 1024 BLOCKS RESIDENT (4 blocks/CU):
// LDS 25600 B (K dbuf 16K + P 9216), VGPR capped 128 via launch_bounds(256,4).
// V is NOT staged in LDS: the 8 PV B-frags are loaded global->reg at the TOP
// of each step and consumed after QK^T+softmax (>=400cy) — L1/L2 latency
// hidden (R4's failure was latency-EXPOSED direct loads). This halves DS
// traffic (the R7 bottleneck mix) and rides the idle TA pipe.
// Balance by construction: blockIdx = s*256 + cuid, cuid = bh*8+g;
// qt(s,g) = {31-g, g, 15-g, 16+g} -> per-cuid step total = 62 for ALL cuid,
// bijective over qt 0..31. Same-CU blocks share bh -> K/V L1/L2-hot.
// Mapping is a balance heuristic only — correctness never depends on it.
// ---------------------------------------------------------------------------
__global__ __launch_bounds__(256, 4) void attn_kernel(
    const bf16* __restrict__ Q, const bf16* __restrict__ Kg,
    const bf16* __restrict__ Vt, bf16* __restrict__ O)
{
    const int t    = threadIdx.x;
    const int lane = t & 63, w = t >> 6;      // w = 0..3
    const int quad = lane >> 4, col = lane & 15;
    const int cuid = blockIdx.x & 255;
    const int s_   = blockIdx.x >> 8;         // 0..3
    const int bh   = cuid >> 3, g = cuid & 7;
    const int qt   = (s_ == 0) ? (31 - g) : (s_ == 1) ? g : (s_ == 2) ? (15 - g) : (16 + g);
    const int b  = bh >> 4, h = bh & 15;
    const float nslope = -EXP2F(-0.5f * (float)(h + 1)) * LOG2E;

    const bf16* qp  = Q  + (size_t)bh * 2048 * 64;
    const bf16* kp  = Kg + (size_t)bh * 2048 * 64;
    const bf16* vtp = Vt + (size_t)bh * 64 * 2048;   // V^T: [64][2048]

    __shared__ alignas(16) bf16 Kbuf[2][64 * 64];
    __shared__ alignas(16) bf16 Ps[4 * 16 * 72];
    bf16* Pw = Ps + w * (16 * 72);

    const int q0 = qt * 64;

    bf16x8 qa[2];
#pragma unroll
    for (int ks = 0; ks < 2; ++ks)
        qa[ks] = *(const bf16x8*)(qp + (size_t)(q0 + w * 16 + col) * 64
                                  + ks * 32 + quad * 8);

    float mrow[4], lrow[4], bi[4];
    f32x4 of[4] = {};
    const int gi0 = q0 + w * 16 + quad * 4;
#pragma unroll
    for (int r = 0; r < 4; ++r) {
        mrow[r] = NEG_BIG; lrow[r] = 0.f;
        bi[r] = nslope * (float)(gi0 + r);
    }

    // prologue: stage K-tile 0 into buffer 0 (512 16B-chunks)
    {
#pragma unroll
        for (int i = 0; i < 2; ++i) {
            int c = i * 256 + t;
            int row = c >> 3, j8 = (c & 7) ^ (row & 7);
            stage16(kp + (size_t)row * 64 + j8 * 8, Kbuf[0] + (i * 256 + w * 64) * 8);
        }
    }
    __syncthreads();

    for (int kvt = 0; kvt <= qt; ++kvt) {
        const int kv0 = kvt * 64;
        const bf16* Kb = Kbuf[kvt & 1];

        // V frags for THIS step: issue global->reg loads NOW, consume them in
        // PV after QK^T + softmax — latency hidden by independent work.
        bf16x8 vc[2][4];
#pragma unroll
        for (int kk = 0; kk < 2; ++kk)
#pragma unroll
            for (int jd = 0; jd < 4; ++jd)
                vc[kk][jd] = *(const bf16x8*)(vtp + (size_t)(jd * 16 + col) * 2048
                                              + kv0 + kk * 32 + quad * 8);

        // prefetch next K tile into the other buffer (async; drained by the
        // end-of-iteration barrier)
        if (kvt < qt) {
            bf16* Kn = Kbuf[(kvt & 1) ^ 1];
            const int nv0 = kv0 + 64;
#pragma unroll
            for (int i = 0; i < 2; ++i) {
                int c = i * 256 + t;
                int row = c >> 3, j8 = (c & 7) ^ (row & 7);
                stage16(kp + (size_t)(nv0 + row) * 64 + j8 * 8, Kn + (i * 256 + w * 64) * 8);
            }
        }

        // S = Q K^T  (swizzled K reads: chunk = (quad + 4*ks) ^ (row&7))
        f32x4 sc[4];
#pragma unroll
        for (int nj = 0; nj < 4; ++nj) {
            const int row = nj * 16 + col;
            const bf16* kb = Kb + row * 64;
            const int rx = row & 7;
            bf16x8 k0f = *(const bf16x8*)(kb + (quad ^ rx) * 8);
            bf16x8 k1f = *(const bf16x8*)(kb + ((quad + 4) ^ rx) * 8);
            f32x4 zz = {};
            zz = __builtin_amdgcn_mfma_f32_16x16x32_bf16(qa[0], k0f, zz, 0, 0, 0);
            zz = __builtin_amdgcn_mfma_f32_16x16x32_bf16(qa[1], k1f, zz, 0, 0, 0);
            sc[nj] = zz;
        }

        // softmax (exp2-domain, DPP reduces, hoisted ALiBi)
        const bool diag = (kvt == qt);
        float bj[4];
#pragma unroll
        for (int nj = 0; nj < 4; ++nj)
            bj[nj] = nslope * (float)(kv0 + nj * 16 + col);

#pragma unroll
        for (int r = 0; r < 4; ++r) {
#pragma unroll
            for (int nj = 0; nj < 4; ++nj)
                sc[nj][r] += bi[r] - bj[nj];
            if (diag) {
                const int gi = gi0 + r;
#pragma unroll
                for (int nj = 0; nj < 4; ++nj)
                    if (kv0 + nj * 16 + col > gi) sc[nj][r] = NEG_BIG;
            }
            float mx = sc[0][r];
#pragma unroll
            for (int nj = 1; nj < 4; ++nj) mx = fmaxf(mx, sc[nj][r]);
            mx = red16_max(mx);
            const float mo = mrow[r];
            const float mn = fmaxf(mo, mx);
            const float alpha = EXP2F(mo - mn);
            float rs = 0.f;
#pragma unroll
            for (int nj = 0; nj < 4; ++nj) {
                float p = EXP2F(sc[nj][r] - mn);
                sc[nj][r] = p;
                rs += p;
            }
            rs = red16_sum(rs);
            mrow[r] = mn;
            lrow[r] = lrow[r] * alpha + rs;
#pragma unroll
            for (int jd = 0; jd < 4; ++jd) of[jd][r] *= alpha;
        }

        // P: C/D -> A-operand layout via private per-wave LDS region
        // (wave-private: no barrier; compiler inserts the lgkmcnt)
#pragma unroll
        for (int nj = 0; nj < 4; ++nj)
#pragma unroll
            for (int r = 0; r < 4; ++r)
                Pw[(quad * 4 + r) * 72 + nj * 16 + col] = (bf16)sc[nj][r];

        // O += P V  (V B-frags from registers, loaded at step top)
#pragma unroll
        for (int kk = 0; kk < 2; ++kk) {
            bf16x8 pa = *(const bf16x8*)(Pw + col * 72 + kk * 32 + quad * 8);
#pragma unroll
            for (int jd = 0; jd < 4; ++jd)
                of[jd] = __builtin_amdgcn_mfma_f32_16x16x32_bf16(pa, vc[kk][jd], of[jd], 0, 0, 0);
        }

        // ONE barrier: (a) everyone done reading Kb before next-iter
        // overwrite, (b) vmcnt drain -> prefetched K tile visible next iter.
        __syncthreads();
    }

    // normalize + write this q-tile's attn output (bf16) to [B,S,E]
#pragma unroll
    for (int r = 0; r < 4; ++r) {
        const int s = q0 + w * 16 + quad * 4 + r;
        const float inv_l = 1.f / lrow[r];
#pragma unroll
        for (int jd = 0; jd < 4; ++jd) {
            const int e = h * 64 + jd * 16 + col;
            O[((size_t)(b * 2048 + s)) * 1024 + e] = (bf16)(of[jd][r] * inv_l);
        }
    }
}

// ---------------------------------------------------------------------------
// Output projection (R7-proven): A bf16 via stage16; Wo f32 via cvt8.
// ---------------------------------------------------------------------------
__global__ __launch_bounds__(256) void out_gemm(
    const bf16* __restrict__ A, const float* __restrict__ W,
    const float* __restrict__ bias, float* __restrict__ out)
{
    __shared__ alignas(16) bf16 As[128 * 32];
    __shared__ alignas(16) bf16 Bs[128 * 32];

    const int t    = threadIdx.x;
    const int lane = t & 63, w = t >> 6;
    const int quad = lane >> 4, col = lane & 15;
    const int n0 = blockIdx.x * 128;
    const int m0 = blockIdx.y * 128;
    const int K  = 1024;
    const int wm = (w >> 1) * 64, wn = (w & 1) * 64;
    const int r0 = t >> 2, c8 = (t & 3) * 8;
    f32x4 acc[4][4] = {};

    for (int k0 = 0; k0 < K; k0 += 32) {
        bf16x8 bx0 = cvt8(W + (size_t)(n0 + r0)      * K + k0 + c8);
        bf16x8 bx1 = cvt8(W + (size_t)(n0 + 64 + r0) * K + k0 + c8);
        __syncthreads();
#pragma unroll
        for (int i = 0; i < 2; ++i) {
            int c = i * 256 + t;
            stage16(A + (size_t)(m0 + (c >> 2)) * K + k0 + (c & 3) * 8,
                    As + (i * 256 + w * 64) * 8);
        }
        *(bf16x8*)(Bs + r0 * 32 + c8)        = bx0;
        *(bf16x8*)(Bs + (64 + r0) * 32 + c8) = bx1;
        __syncthreads();

        bf16x8 a[4], b[4];
#pragma unroll
        for (int i = 0; i < 4; ++i)
            a[i] = *(const bf16x8*)(As + (wm + i * 16 + col) * 32 + quad * 8);
#pragma unroll
        for (int j = 0; j < 4; ++j)
            b[j] = *(const bf16x8*)(Bs + (wn + j * 16 + col) * 32 + quad * 8);
#pragma unroll
        for (int i = 0; i < 4; ++i)
#pragma unroll
            for (int j = 0; j < 4; ++j)
                acc[i][j] = __builtin_amdgcn_mfma_f32_16x16x32_bf16(a[i], b[j], acc[i][j], 0, 0, 0);
    }

#pragma unroll
    for (int i = 0; i < 4; ++i) {
        const int mbase = m0 + wm + i * 16 + quad * 4;
#pragma unroll
        for (int j = 0; j < 4; ++j) {
            const int n = n0 + wn + j * 16 + col;
            const float bb = bias[n];
#pragma unroll
            for (int r = 0; r < 4; ++r)
                out[(size_t)(mbase + r) * 1024 + n] = acc[i][j][r] + bb;
        }
    }
}

extern "C" void kernel_launch(void* const* d_in, const int* in_sizes, int n_in,
                              void* d_out, int out_size, void* d_ws, size_t ws_size,
                              hipStream_t stream) {
    const float* x  = (const float*)d_in[0];
    const float* Wq = (const float*)d_in[1];
    const float* bq = (const float*)d_in[2];
    const float* Wk = (const float*)d_in[3];
    const float* bk = (const float*)d_in[4];
    const float* Wv = (const float*)d_in[5];
    const float* bv = (const float*)d_in[6];
    const float* Wo = (const float*)d_in[7];
    const float* bo = (const float*)d_in[8];
    float* out = (float*)d_out;

    // ws (32 MB, proven): [xb | q | k | v^T] bf16; attn output aliases xb.
    bf16* xb  = (bf16*)d_ws;
    bf16* qws = xb  + 4194304;
    bf16* kws = qws + 4194304;
    bf16* vws = kws + 4194304;
    bf16* aws = xb;

    // d_out scratch: bf16 Wq|Wk|Wv (6 MB); dead before out_gemm writes.
    bf16* wb = (bf16*)d_out;

    conv_all<<<dim3(3584), 256, 0, stream>>>(x, Wq, Wk, Wv, xb, wb);
    qkv_gemm<<<dim3(24, 32), 256, 0, stream>>>(xb, wb, bq, bk, bv, qws, kws, vws);
    attn_kernel<<<dim3(1024), 256, 0, stream>>>(qws, kws, vws, aws);
    out_gemm<<<dim3(8, 32), 256, 0, stream>>>(aws, Wo, bo, out);
}

// Round 10
// 213.162 us; speedup vs baseline: 1.1809x; 1.1809x over previous
//
#include <hip/hip_runtime.h>
#include <hip/hip_bf16.h>

typedef __bf16 bf16;
typedef __bf16 bf16x4 __attribute__((ext_vector_type(4)));
typedef __bf16 bf16x8 __attribute__((ext_vector_type(8)));
typedef float  f32x4  __attribute__((ext_vector_type(4)));

#define NEG_BIG (-1e30f)
#define LOG2E 1.44269504088896340736f

#define AS1(p) ((const __attribute__((address_space(1))) void*)(p))
#define AS3(p) ((__attribute__((address_space(3))) void*)(p))

// async global->LDS, 16B/lane; dest = wave-uniform base + lane*16 (m104/m108)
__device__ __forceinline__ void stage16(const void* g, void* lds_uniform_base) {
    __builtin_amdgcn_global_load_lds(AS1(g), AS3(lds_uniform_base), 16, 0, 0);
}

__device__ __forceinline__ bf16x8 cvt8(const float* __restrict__ p) {
    bf16x8 r;
#pragma unroll
    for (int i = 0; i < 8; ++i) r[i] = (bf16)p[i];
    return r;
}

// ---- DPP butterfly reduce over 16 consecutive lanes (pure VALU, no LDS) ----
template <int CTRL>
__device__ __forceinline__ float dpp_max_step(float x) {
    int v = __builtin_bit_cast(int, x);
    int s = __builtin_amdgcn_update_dpp(v, v, CTRL, 0xF, 0xF, true);
    return fmaxf(x, __builtin_bit_cast(float, s));
}
template <int CTRL>
__device__ __forceinline__ float dpp_add_step(float x) {
    int v = __builtin_bit_cast(int, x);
    int s = __builtin_amdgcn_update_dpp(v, v, CTRL, 0xF, 0xF, true);
    return x + __builtin_bit_cast(float, s);
}
__device__ __forceinline__ float red16_max(float x) {
    x = dpp_max_step<0xB1>(x);
    x = dpp_max_step<0x4E>(x);
    x = dpp_max_step<0x141>(x);
    x = dpp_max_step<0x140>(x);
    return x;
}
__device__ __forceinline__ float red16_sum(float x) {
    x = dpp_add_step<0xB1>(x);
    x = dpp_add_step<0x4E>(x);
    x = dpp_add_step<0x141>(x);
    x = dpp_add_step<0x140>(x);
    return x;
}

#if __has_builtin(__builtin_amdgcn_exp2f)
#define EXP2F(x) __builtin_amdgcn_exp2f(x)
#else
#define EXP2F(x) exp2f(x)
#endif

// ---------------------------------------------------------------------------
// Part table (compile-time, LPT order: longest parts first in blockIdx).
// {qt, kv_begin, nsteps, pslot}: pslot<0 -> direct O write; else partial slot
// (qt-16)*2 + isB. Tiles 0..15 unsplit; tiles 16..31 split into 2 halves.
// Coverage: per tile, parts' [kv_begin, kv_begin+nsteps) tile the range
// [0, qt+1). Order is a packing heuristic only — never correctness.
// ---------------------------------------------------------------------------
__device__ const int4 PART_TAB[48] = {
    {31, 0,16,30},{31,16,16,31},{30, 0,16,28},{15, 0,16,-1},
    {30,16,15,29},{29, 0,15,26},{29,15,15,27},{28, 0,15,24},{14, 0,15,-1},
    {28,15,14,25},{27, 0,14,22},{27,14,14,23},{26, 0,14,20},{13, 0,14,-1},
    {26,14,13,21},{25, 0,13,18},{25,13,13,19},{24, 0,13,16},{12, 0,13,-1},
    {24,13,12,17},{23, 0,12,14},{23,12,12,15},{22, 0,12,12},{11, 0,12,-1},
    {22,12,11,13},{21, 0,11,10},{21,11,11,11},{20, 0,11, 8},{10, 0,11,-1},
    {20,11,10, 9},{19, 0,10, 6},{19,10,10, 7},{18, 0,10, 4},{ 9, 0,10,-1},
    {18,10, 9, 5},{17, 0, 9, 2},{17, 9, 9, 3},{16, 0, 9, 0},{ 8, 0, 9,-1},
    {16, 9, 8, 1},
    { 7, 0, 8,-1},{ 6, 0, 7,-1},{ 5, 0, 6,-1},{ 4, 0, 5,-1},
    { 3, 0, 4,-1},{ 2, 0, 3,-1},{ 1, 0, 2,-1},{ 0, 0, 1,-1}
};

// ---------------------------------------------------------------------------
// f32->bf16: x -> xb (ws), Wq/Wk/Wv -> wb (d_out scratch). (R7-proven.)
// ---------------------------------------------------------------------------
__global__ __launch_bounds__(256) void conv_all(
    const float* __restrict__ x,  const float* __restrict__ wq,
    const float* __restrict__ wk, const float* __restrict__ wv,
    bf16* __restrict__ xb, bf16* __restrict__ wb)
{
    const int blk = blockIdx.x;
    const float* src; bf16* dst; size_t off;
    if (blk < 2048)      { src = x;  dst = xb;           off = (size_t)blk * 2048; }
    else if (blk < 2560) { src = wq; dst = wb;           off = (size_t)(blk - 2048) * 2048; }
    else if (blk < 3072) { src = wk; dst = wb + 1048576; off = (size_t)(blk - 2560) * 2048; }
    else                 { src = wv; dst = wb + 2097152; off = (size_t)(blk - 3072) * 2048; }
    const size_t i = off + (size_t)threadIdx.x * 8;
    *(bf16x8*)(dst + i) = cvt8(src + i);
}

// ---------------------------------------------------------------------------
// Fused QKV projection, all-bf16 (R7-proven core). y = xb @ Wb.T + b.
// Q is scaled by 0.125*log2e (exp2-domain softmax). V is written TRANSPOSED:
// V^T[bh][64][2048] so attn can stage it with global_load_lds (no transpose).
// ---------------------------------------------------------------------------
__global__ __launch_bounds__(256) void qkv_gemm(
    const bf16* __restrict__ Xb, const bf16* __restrict__ Wb,
    const float* __restrict__ bq, const float* __restrict__ bk, const float* __restrict__ bv,
    bf16* __restrict__ qo, bf16* __restrict__ ko, bf16* __restrict__ vo)
{
    __shared__ alignas(16) bf16 As[128 * 32];
    __shared__ alignas(16) bf16 Bs[128 * 32];

    const int t    = threadIdx.x;
    const int lane = t & 63, w = t >> 6;
    const int quad = lane >> 4, col = lane & 15;
    const int nt = blockIdx.x;            // 0..23
    const int mt = blockIdx.y;            // 0..31
    const int region = nt >> 3;           // 0=q 1=k 2=v
    const int n0 = (nt & 7) * 128;
    const int m0 = mt * 128;
    const int K  = 1024;

    const bf16*  W    = Wb + (size_t)region * 1048576;
    const float* bias = region == 0 ? bq : (region == 1 ? bk : bv);

    const int wm = (w >> 1) * 64, wn = (w & 1) * 64;
    f32x4 acc[4][4] = {};

    for (int k0 = 0; k0 < K; k0 += 32) {
        __syncthreads();
#pragma unroll
        for (int i = 0; i < 2; ++i) {
            int c = i * 256 + t;
            stage16(Xb + (size_t)(m0 + (c >> 2)) * K + k0 + (c & 3) * 8,
                    As + (i * 256 + w * 64) * 8);
        }
#pragma unroll
        for (int i = 0; i < 2; ++i) {
            int c = i * 256 + t;
            stage16(W + (size_t)(n0 + (c >> 2)) * K + k0 + (c & 3) * 8,
                    Bs + (i * 256 + w * 64) * 8);
        }
        __syncthreads();

        bf16x8 a[4], b[4];
#pragma unroll
        for (int i = 0; i < 4; ++i)
            a[i] = *(const bf16x8*)(As + (wm + i * 16 + col) * 32 + quad * 8);
#pragma unroll
        for (int j = 0; j < 4; ++j)
            b[j] = *(const bf16x8*)(Bs + (wn + j * 16 + col) * 32 + quad * 8);
#pragma unroll
        for (int i = 0; i < 4; ++i)
#pragma unroll
            for (int j = 0; j < 4; ++j)
                acc[i][j] = __builtin_amdgcn_mfma_f32_16x16x32_bf16(a[i], b[j], acc[i][j], 0, 0, 0);
    }

    if (region == 2) {
        // V^T epilogue: rows d = n&63, cols s (contiguous in r) -> packed 8B stores
#pragma unroll
        for (int i = 0; i < 4; ++i) {
            const int mbase = m0 + wm + i * 16 + quad * 4;
            const int b_ = mbase >> 11, s = mbase & 2047;
#pragma unroll
            for (int j = 0; j < 4; ++j) {
                const int n = n0 + wn + j * 16 + col;
                const float bb = bias[n];
                const int h = n >> 6, d = n & 63;
                bf16x4 pk;
#pragma unroll
                for (int r = 0; r < 4; ++r) pk[r] = (bf16)(acc[i][j][r] + bb);
                *(bf16x4*)(vo + ((size_t)(b_ * 16 + h) * 64 + d) * 2048 + s) = pk;
            }
        }
    } else {
        bf16* out = region == 0 ? qo : ko;
        const float scale = region == 0 ? (0.125f * LOG2E) : 1.0f;
#pragma unroll
        for (int i = 0; i < 4; ++i) {
            const int mbase = m0 + wm + i * 16 + quad * 4;
#pragma unroll
            for (int j = 0; j < 4; ++j) {
                const int n = n0 + wn + j * 16 + col;
                const float bb = bias[n];
                const int h = n >> 6, d = n & 63;
#pragma unroll
                for (int r = 0; r < 4; ++r) {
                    const int m  = mbase + r;
                    const int b_ = m >> 11, s = m & 2047;
                    out[(((size_t)(b_ * 16 + h)) * 2048 + s) * 64 + d] =
                        (bf16)((acc[i][j][r] + bb) * scale);
                }
            }
        }
    }
}

// ---------------------------------------------------------------------------
// Flash attention — R7 inner loop VERBATIM, but each block runs one PART of a
// q-tile's kv range (PART_TAB): tiles 0..15 unsplit (direct write), tiles
// 16..31 split into 2 kv-halves, each emitting an online-softmax partial
// (m, l, O/l) to d_out scratch; merge_kernel combines. Part length <= 16
// steps bounds the serial kv-sweep; grid 1536 = 6 blocks/CU queued, 4
// resident (LDS 25.6KB, launch_bounds(256,4)) -> slots backfill, LPT order.
// ---------------------------------------------------------------------------
__global__ __launch_bounds__(256, 4) void attn_kernel(
    const bf16* __restrict__ Q, const bf16* __restrict__ Kg,
    const bf16* __restrict__ Vt, bf16* __restrict__ O,
    bf16* __restrict__ Opart, float2* __restrict__ ML)
{
    const int t    = threadIdx.x;
    const int lane = t & 63, w = t >> 6;      // w = 0..3
    const int quad = lane >> 4, col = lane & 15;
    const int bh   = blockIdx.x & 31;
    const int pe   = blockIdx.x >> 5;         // 0..47
    const int4 ent = PART_TAB[pe];
    const int qt = ent.x, kvb = ent.y, kstop = ent.y + ent.z, ps = ent.w;
    const int b  = bh >> 4, h = bh & 15;
    const float nslope = -EXP2F(-0.5f * (float)(h + 1)) * LOG2E;

    const bf16* qp  = Q  + (size_t)bh * 2048 * 64;
    const bf16* kp  = Kg + (size_t)bh * 2048 * 64;
    const bf16* vtp = Vt + (size_t)bh * 64 * 2048;   // V^T: [64][2048]

    __shared__ alignas(16) bf16 Kbuf[2][64 * 64];
    __shared__ alignas(16) bf16 Vbuf[2][64 * 64];
    __shared__ alignas(16) bf16 Ps[4 * 16 * 72];
    bf16* Pw = Ps + w * (16 * 72);

    const int q0 = qt * 64;

    bf16x8 qa[2];
#pragma unroll
    for (int ks = 0; ks < 2; ++ks)
        qa[ks] = *(const bf16x8*)(qp + (size_t)(q0 + w * 16 + col) * 64
                                  + ks * 32 + quad * 8);

    float mrow[4], lrow[4], bi[4];
    f32x4 of[4] = {};
    const int gi0 = q0 + w * 16 + quad * 4;
#pragma unroll
    for (int r = 0; r < 4; ++r) {
        mrow[r] = NEG_BIG; lrow[r] = 0.f;
        bi[r] = nslope * (float)(gi0 + r);
    }

    // prologue: stage kv-tile kvb into buffer 0 (512 16B-chunks each)
    {
        const int v0 = kvb * 64;
#pragma unroll
        for (int i = 0; i < 2; ++i) {
            int c = i * 256 + t;
            int row = c >> 3, j8 = (c & 7) ^ (row & 7);
            stage16(kp + (size_t)(v0 + row) * 64 + j8 * 8, Kbuf[0] + (i * 256 + w * 64) * 8);
        }
#pragma unroll
        for (int i = 0; i < 2; ++i) {
            int c = i * 256 + t;
            int d = c >> 3, j8 = (c & 7) ^ (d & 7);
            stage16(vtp + (size_t)d * 2048 + v0 + j8 * 8, Vbuf[0] + (i * 256 + w * 64) * 8);
        }
    }
    __syncthreads();

    for (int kvt = kvb; kvt < kstop; ++kvt) {
        const int kv0 = kvt * 64;
        const int pb  = (kvt - kvb) & 1;
        const bf16* Kb = Kbuf[pb];
        const bf16* Vb = Vbuf[pb];

        // prefetch next tile into the other buffer (async; drained by the
        // end-of-iteration barrier)
        if (kvt + 1 < kstop) {
            bf16* Kn = Kbuf[pb ^ 1];
            bf16* Vn = Vbuf[pb ^ 1];
            const int nv0 = kv0 + 64;
#pragma unroll
            for (int i = 0; i < 2; ++i) {
                int c = i * 256 + t;
                int row = c >> 3, j8 = (c & 7) ^ (row & 7);
                stage16(kp + (size_t)(nv0 + row) * 64 + j8 * 8, Kn + (i * 256 + w * 64) * 8);
            }
#pragma unroll
            for (int i = 0; i < 2; ++i) {
                int c = i * 256 + t;
                int d = c >> 3, j8 = (c & 7) ^ (d & 7);
                stage16(vtp + (size_t)d * 2048 + nv0 + j8 * 8, Vn + (i * 256 + w * 64) * 8);
            }
        }

        // S = Q K^T  (swizzled K reads: chunk = (quad + 4*ks) ^ (row&7))
        f32x4 sc[4];
#pragma unroll
        for (int nj = 0; nj < 4; ++nj) {
            const int row = nj * 16 + col;
            const bf16* kb = Kb + row * 64;
            const int rx = row & 7;
            bf16x8 k0f = *(const bf16x8*)(kb + (quad ^ rx) * 8);
            bf16x8 k1f = *(const bf16x8*)(kb + ((quad + 4) ^ rx) * 8);
            f32x4 zz = {};
            zz = __builtin_amdgcn_mfma_f32_16x16x32_bf16(qa[0], k0f, zz, 0, 0, 0);
            zz = __builtin_amdgcn_mfma_f32_16x16x32_bf16(qa[1], k1f, zz, 0, 0, 0);
            sc[nj] = zz;
        }

        // softmax (exp2-domain, DPP reduces, hoisted ALiBi)
        const bool diag = (kvt == qt);
        float bj[4];
#pragma unroll
        for (int nj = 0; nj < 4; ++nj)
            bj[nj] = nslope * (float)(kv0 + nj * 16 + col);

#pragma unroll
        for (int r = 0; r < 4; ++r) {
#pragma unroll
            for (int nj = 0; nj < 4; ++nj)
                sc[nj][r] += bi[r] - bj[nj];
            if (diag) {
                const int gi = gi0 + r;
#pragma unroll
                for (int nj = 0; nj < 4; ++nj)
                    if (kv0 + nj * 16 + col > gi) sc[nj][r] = NEG_BIG;
            }
            float mx = sc[0][r];
#pragma unroll
            for (int nj = 1; nj < 4; ++nj) mx = fmaxf(mx, sc[nj][r]);
            mx = red16_max(mx);
            const float mo = mrow[r];
            const float mn = fmaxf(mo, mx);
            const float alpha = EXP2F(mo - mn);
            float rs = 0.f;
#pragma unroll
            for (int nj = 0; nj < 4; ++nj) {
                float p = EXP2F(sc[nj][r] - mn);
                sc[nj][r] = p;
                rs += p;
            }
            rs = red16_sum(rs);
            mrow[r] = mn;
            lrow[r] = lrow[r] * alpha + rs;
#pragma unroll
            for (int jd = 0; jd < 4; ++jd) of[jd][r] *= alpha;
        }

        // P: C/D -> A-operand layout via private per-wave LDS region
        // (wave-private: no barrier; compiler inserts the lgkmcnt)
#pragma unroll
        for (int nj = 0; nj < 4; ++nj)
#pragma unroll
            for (int r = 0; r < 4; ++r)
                Pw[(quad * 4 + r) * 72 + nj * 16 + col] = (bf16)sc[nj][r];

        // O += P V  (swizzled V reads: chunk = (kk*4+quad) ^ (d&7))
#pragma unroll
        for (int kk = 0; kk < 2; ++kk) {
            bf16x8 pa = *(const bf16x8*)(Pw + col * 72 + kk * 32 + quad * 8);
#pragma unroll
            for (int jd = 0; jd < 4; ++jd) {
                const int rd = jd * 16 + col;
                bf16x8 vbf = *(const bf16x8*)(Vb + rd * 64 + (((kk * 4 + quad) ^ (rd & 7)) * 8));
                of[jd] = __builtin_amdgcn_mfma_f32_16x16x32_bf16(pa, vbf, of[jd], 0, 0, 0);
            }
        }

        // ONE barrier: (a) everyone done reading Kb/Vb before next-iter
        // overwrite, (b) vmcnt drain -> prefetched tile visible next iter.
        __syncthreads();
    }

    if (ps < 0) {
        // direct: normalize + write this q-tile's attn output to [B,S,E]
#pragma unroll
        for (int r = 0; r < 4; ++r) {
            const int s = q0 + w * 16 + quad * 4 + r;
            const float inv_l = 1.f / lrow[r];
#pragma unroll
            for (int jd = 0; jd < 4; ++jd) {
                const int e = h * 64 + jd * 16 + col;
                O[((size_t)(b * 2048 + s)) * 1024 + e] = (bf16)(of[jd][r] * inv_l);
            }
        }
    } else {
        // partial: write O/l (bf16) + per-row (m, l) to scratch
        const size_t base = ((size_t)(bh * 32 + ps)) * 64;
#pragma unroll
        for (int r = 0; r < 4; ++r) {
            const int row = w * 16 + quad * 4 + r;
            const float inv_l = 1.f / lrow[r];
#pragma unroll
            for (int jd = 0; jd < 4; ++jd)
                Opart[(base + row) * 64 + jd * 16 + col] = (bf16)(of[jd][r] * inv_l);
            if (col == 0)
                ML[base + row] = make_float2(mrow[r], lrow[r]);
        }
    }
}

// ---------------------------------------------------------------------------
// Merge: combine the 2 kv-half partials of each split tile (qt 16..31).
// out = (O0*w0 + O1*w1) / (w0+w1), wi = li * 2^(mi - max(m0,m1)).
// ---------------------------------------------------------------------------
__global__ __launch_bounds__(256) void merge_kernel(
    const bf16* __restrict__ Opart, const float2* __restrict__ ML,
    bf16* __restrict__ O)
{
    const int bh = blockIdx.x & 31;
    const int qt = 16 + (blockIdx.x >> 5);
    const int b = bh >> 4, h = bh & 15;
    const int p0 = (qt - 16) * 2, p1 = p0 + 1;
    const int t = threadIdx.x;
    const int row = t >> 2, d0 = (t & 3) * 16;

    const float2 ml0 = ML[(size_t)(bh * 32 + p0) * 64 + row];
    const float2 ml1 = ML[(size_t)(bh * 32 + p1) * 64 + row];
    const float mt = fmaxf(ml0.x, ml1.x);
    float w0 = ml0.y * EXP2F(ml0.x - mt);
    float w1 = ml1.y * EXP2F(ml1.x - mt);
    const float inv = 1.f / (w0 + w1);
    w0 *= inv; w1 *= inv;

    const bf16* a = Opart + ((size_t)(bh * 32 + p0) * 64 + row) * 64 + d0;
    const bf16* c = Opart + ((size_t)(bh * 32 + p1) * 64 + row) * 64 + d0;
    bf16* o = O + ((size_t)(b * 2048 + qt * 64 + row)) * 1024 + h * 64 + d0;

#pragma unroll
    for (int i = 0; i < 2; ++i) {
        bf16x8 va = *(const bf16x8*)(a + i * 8);
        bf16x8 vc = *(const bf16x8*)(c + i * 8);
        bf16x8 vo;
#pragma unroll
        for (int e = 0; e < 8; ++e)
            vo[e] = (bf16)((float)va[e] * w0 + (float)vc[e] * w1);
        *(bf16x8*)(o + i * 8) = vo;
    }
}

// ---------------------------------------------------------------------------
// Output projection (R7-proven): A bf16 via stage16; Wo f32 via cvt8.
// ---------------------------------------------------------------------------
__global__ __launch_bounds__(256) void out_gemm(
    const bf16* __restrict__ A, const float* __restrict__ W,
    const float* __restrict__ bias, float* __restrict__ out)
{
    __shared__ alignas(16) bf16 As[128 * 32];
    __shared__ alignas(16) bf16 Bs[128 * 32];

    const int t    = threadIdx.x;
    const int lane = t & 63, w = t >> 6;
    const int quad = lane >> 4, col = lane & 15;
    const int n0 = blockIdx.x * 128;
    const int m0 = blockIdx.y * 128;
    const int K  = 1024;
    const int wm = (w >> 1) * 64, wn = (w & 1) * 64;
    const int r0 = t >> 2, c8 = (t & 3) * 8;
    f32x4 acc[4][4] = {};

    for (int k0 = 0; k0 < K; k0 += 32) {
        bf16x8 bx0 = cvt8(W + (size_t)(n0 + r0)      * K + k0 + c8);
        bf16x8 bx1 = cvt8(W + (size_t)(n0 + 64 + r0) * K + k0 + c8);
        __syncthreads();
#pragma unroll
        for (int i = 0; i < 2; ++i) {
            int c = i * 256 + t;
            stage16(A + (size_t)(m0 + (c >> 2)) * K + k0 + (c & 3) * 8,
                    As + (i * 256 + w * 64) * 8);
        }
        *(bf16x8*)(Bs + r0 * 32 + c8)        = bx0;
        *(bf16x8*)(Bs + (64 + r0) * 32 + c8) = bx1;
        __syncthreads();

        bf16x8 a[4], b[4];
#pragma unroll
        for (int i = 0; i < 4; ++i)
            a[i] = *(const bf16x8*)(As + (wm + i * 16 + col) * 32 + quad * 8);
#pragma unroll
        for (int j = 0; j < 4; ++j)
            b[j] = *(const bf16x8*)(Bs + (wn + j * 16 + col) * 32 + quad * 8);
#pragma unroll
        for (int i = 0; i < 4; ++i)
#pragma unroll
            for (int j = 0; j < 4; ++j)
                acc[i][j] = __builtin_amdgcn_mfma_f32_16x16x32_bf16(a[i], b[j], acc[i][j], 0, 0, 0);
    }

#pragma unroll
    for (int i = 0; i < 4; ++i) {
        const int mbase = m0 + wm + i * 16 + quad * 4;
#pragma unroll
        for (int j = 0; j < 4; ++j) {
            const int n = n0 + wn + j * 16 + col;
            const float bb = bias[n];
#pragma unroll
            for (int r = 0; r < 4; ++r)
                out[(size_t)(mbase + r) * 1024 + n] = acc[i][j][r] + bb;
        }
    }
}

extern "C" void kernel_launch(void* const* d_in, const int* in_sizes, int n_in,
                              void* d_out, int out_size, void* d_ws, size_t ws_size,
                              hipStream_t stream) {
    const float* x  = (const float*)d_in[0];
    const float* Wq = (const float*)d_in[1];
    const float* bq = (const float*)d_in[2];
    const float* Wk = (const float*)d_in[3];
    const float* bk = (const float*)d_in[4];
    const float* Wv = (const float*)d_in[5];
    const float* bv = (const float*)d_in[6];
    const float* Wo = (const float*)d_in[7];
    const float* bo = (const float*)d_in[8];
    float* out = (float*)d_out;

    // ws (32 MB, proven): [xb | q | k | v^T] bf16; attn output aliases xb.
    bf16* xb  = (bf16*)d_ws;
    bf16* qws = xb  + 4194304;
    bf16* kws = qws + 4194304;
    bf16* vws = kws + 4194304;
    bf16* aws = xb;

    // d_out scratch (16.7 MB):
    //   [0, 6MB):   wb, bf16 Wq|Wk|Wv — dead after qkv_gemm.
    //   [0, 8MB):   Opart (bf16, 32bh x 32slots x 64x64) — attn overwrites wb.
    //   [8, 8.5MB): ML (float2, 32bh x 32slots x 64 rows).
    // All dead before out_gemm writes out.
    bf16*   wb    = (bf16*)d_out;
    bf16*   opart = (bf16*)d_out;
    float2* ml    = (float2*)((char*)d_out + 8u * 1024 * 1024);

    conv_all<<<dim3(3584), 256, 0, stream>>>(x, Wq, Wk, Wv, xb, wb);
    qkv_gemm<<<dim3(24, 32), 256, 0, stream>>>(xb, wb, bq, bk, bv, qws, kws, vws);
    attn_kernel<<<dim3(1536), 256, 0, stream>>>(qws, kws, vws, aws, opart, ml);
    merge_kernel<<<dim3(512), 256, 0, stream>>>(opart, ml, aws);
    out_gemm<<<dim3(8, 32), 256, 0, stream>>>(aws, Wo, bo, out);
}

// Round 12
// 195.841 us; speedup vs baseline: 1.2853x; 1.0884x over previous
//
#include <hip/hip_runtime.h>
#include <hip/hip_bf16.h>

typedef __bf16 bf16;
typedef __bf16 bf16x4 __attribute__((ext_vector_type(4)));
typedef __bf16 bf16x8 __attribute__((ext_vector_type(8)));
typedef float  f32x4  __attribute__((ext_vector_type(4)));

#define NEG_BIG (-1e30f)
#define LOG2E 1.44269504088896340736f

#define AS1(p) ((const __attribute__((address_space(1))) void*)(p))
#define AS3(p) ((__attribute__((address_space(3))) void*)(p))

// async global->LDS, 16B/lane; dest = wave-uniform base + lane*16 (m104/m108)
__device__ __forceinline__ void stage16(const void* g, void* lds_uniform_base) {
    __builtin_amdgcn_global_load_lds(AS1(g), AS3(lds_uniform_base), 16, 0, 0);
}

__device__ __forceinline__ bf16x8 cvt8(const float* __restrict__ p) {
    bf16x8 r;
#pragma unroll
    for (int i = 0; i < 8; ++i) r[i] = (bf16)p[i];
    return r;
}

// ---- DPP butterfly reduce over 16 consecutive lanes (pure VALU, no LDS) ----
template <int CTRL>
__device__ __forceinline__ float dpp_max_step(float x) {
    int v = __builtin_bit_cast(int, x);
    int s = __builtin_amdgcn_update_dpp(v, v, CTRL, 0xF, 0xF, true);
    return fmaxf(x, __builtin_bit_cast(float, s));
}
template <int CTRL>
__device__ __forceinline__ float dpp_add_step(float x) {
    int v = __builtin_bit_cast(int, x);
    int s = __builtin_amdgcn_update_dpp(v, v, CTRL, 0xF, 0xF, true);
    return x + __builtin_bit_cast(float, s);
}
__device__ __forceinline__ float red16_max(float x) {
    x = dpp_max_step<0xB1>(x);
    x = dpp_max_step<0x4E>(x);
    x = dpp_max_step<0x141>(x);
    x = dpp_max_step<0x140>(x);
    return x;
}
__device__ __forceinline__ float red16_sum(float x) {
    x = dpp_add_step<0xB1>(x);
    x = dpp_add_step<0x4E>(x);
    x = dpp_add_step<0x141>(x);
    x = dpp_add_step<0x140>(x);
    return x;
}

#if __has_builtin(__builtin_amdgcn_exp2f)
#define EXP2F(x) __builtin_amdgcn_exp2f(x)
#else
#define EXP2F(x) exp2f(x)
#endif

// ---------------------------------------------------------------------------
// f32->bf16: x -> xb (ws), Wq/Wk/Wv -> wb (d_out scratch). (R7-proven.)
// ---------------------------------------------------------------------------
__global__ __launch_bounds__(256) void conv_all(
    const float* __restrict__ x,  const float* __restrict__ wq,
    const float* __restrict__ wk, const float* __restrict__ wv,
    bf16* __restrict__ xb, bf16* __restrict__ wb)
{
    const int blk = blockIdx.x;
    const float* src; bf16* dst; size_t off;
    if (blk < 2048)      { src = x;  dst = xb;           off = (size_t)blk * 2048; }
    else if (blk < 2560) { src = wq; dst = wb;           off = (size_t)(blk - 2048) * 2048; }
    else if (blk < 3072) { src = wk; dst = wb + 1048576; off = (size_t)(blk - 2560) * 2048; }
    else                 { src = wv; dst = wb + 2097152; off = (size_t)(blk - 3072) * 2048; }
    const size_t i = off + (size_t)threadIdx.x * 8;
    *(bf16x8*)(dst + i) = cvt8(src + i);
}

// ---------------------------------------------------------------------------
// Wo f32 -> bf16 into qws (dead after attn; stream order serializes). 4 MB read.
// ---------------------------------------------------------------------------
__global__ __launch_bounds__(256) void conv_wo(
    const float* __restrict__ w, bf16* __restrict__ wb)
{
    const size_t i = ((size_t)blockIdx.x * 256 + threadIdx.x) * 8;
    *(bf16x8*)(wb + i) = cvt8(w + i);
}

// ---------------------------------------------------------------------------
// Fused QKV projection, all-bf16 (R7-proven core). y = xb @ Wb.T + b.
// Q is scaled by 0.125*log2e (exp2-domain softmax). V is written TRANSPOSED:
// V^T[bh][64][2048] so attn can stage it with global_load_lds (no transpose).
// Grid swapped to (mt, nt): consecutive blocks share the B panel (L2 heuristic).
// ---------------------------------------------------------------------------
__global__ __launch_bounds__(256) void qkv_gemm(
    const bf16* __restrict__ Xb, const bf16* __restrict__ Wb,
    const float* __restrict__ bq, const float* __restrict__ bk, const float* __restrict__ bv,
    bf16* __restrict__ qo, bf16* __restrict__ ko, bf16* __restrict__ vo)
{
    __shared__ alignas(16) bf16 As[128 * 32];
    __shared__ alignas(16) bf16 Bs[128 * 32];

    const int t    = threadIdx.x;
    const int lane = t & 63, w = t >> 6;
    const int quad = lane >> 4, col = lane & 15;
    const int mt = blockIdx.x;            // 0..31
    const int nt = blockIdx.y;            // 0..23
    const int region = nt >> 3;           // 0=q 1=k 2=v
    const int n0 = (nt & 7) * 128;
    const int m0 = mt * 128;
    const int K  = 1024;

    const bf16*  W    = Wb + (size_t)region * 1048576;
    const float* bias = region == 0 ? bq : (region == 1 ? bk : bv);

    const int wm = (w >> 1) * 64, wn = (w & 1) * 64;
    f32x4 acc[4][4] = {};

    for (int k0 = 0; k0 < K; k0 += 32) {
        __syncthreads();
#pragma unroll
        for (int i = 0; i < 2; ++i) {
            int c = i * 256 + t;
            stage16(Xb + (size_t)(m0 + (c >> 2)) * K + k0 + (c & 3) * 8,
                    As + (i * 256 + w * 64) * 8);
        }
#pragma unroll
        for (int i = 0; i < 2; ++i) {
            int c = i * 256 + t;
            stage16(W + (size_t)(n0 + (c >> 2)) * K + k0 + (c & 3) * 8,
                    Bs + (i * 256 + w * 64) * 8);
        }
        __syncthreads();

        bf16x8 a[4], b[4];
#pragma unroll
        for (int i = 0; i < 4; ++i)
            a[i] = *(const bf16x8*)(As + (wm + i * 16 + col) * 32 + quad * 8);
#pragma unroll
        for (int j = 0; j < 4; ++j)
            b[j] = *(const bf16x8*)(Bs + (wn + j * 16 + col) * 32 + quad * 8);
#pragma unroll
        for (int i = 0; i < 4; ++i)
#pragma unroll
            for (int j = 0; j < 4; ++j)
                acc[i][j] = __builtin_amdgcn_mfma_f32_16x16x32_bf16(a[i], b[j], acc[i][j], 0, 0, 0);
    }

    if (region == 2) {
        // V^T epilogue: rows d = n&63, cols s (contiguous in r) -> packed 8B stores
#pragma unroll
        for (int i = 0; i < 4; ++i) {
            const int mbase = m0 + wm + i * 16 + quad * 4;
            const int b_ = mbase >> 11, s = mbase & 2047;
#pragma unroll
            for (int j = 0; j < 4; ++j) {
                const int n = n0 + wn + j * 16 + col;
                const float bb = bias[n];
                const int h = n >> 6, d = n & 63;
                bf16x4 pk;
#pragma unroll
                for (int r = 0; r < 4; ++r) pk[r] = (bf16)(acc[i][j][r] + bb);
                *(bf16x4*)(vo + ((size_t)(b_ * 16 + h) * 64 + d) * 2048 + s) = pk;
            }
        }
    } else {
        bf16* out = region == 0 ? qo : ko;
        const float scale = region == 0 ? (0.125f * LOG2E) : 1.0f;
#pragma unroll
        for (int i = 0; i < 4; ++i) {
            const int mbase = m0 + wm + i * 16 + quad * 4;
#pragma unroll
            for (int j = 0; j < 4; ++j) {
                const int n = n0 + wn + j * 16 + col;
                const float bb = bias[n];
                const int h = n >> 6, d = n & 63;
#pragma unroll
                for (int r = 0; r < 4; ++r) {
                    const int m  = mbase + r;
                    const int b_ = m >> 11, s = m & 2047;
                    out[(((size_t)(b_ * 16 + h)) * 2048 + s) * 64 + d] =
                        (bf16)((acc[i][j][r] + bb) * scale);
                }
            }
        }
    }
}

// ---------------------------------------------------------------------------
// Flash attention — R7-EXACT (proven 54us, passing): 64-row q-tiles, grid =
// 32 tiles x 32 bh = 1024 blocks x 256 thr (4 waves x 16 q-rows), LPT
// longest-first (qt = 31-z), LDS 41984 B, stage16 K/V both-sides XOR
// swizzle, dbuf, 1 barrier/step, DPP softmax reduces, exp2 domain.
// ---------------------------------------------------------------------------
__global__ __launch_bounds__(256, 3) void attn_kernel(
    const bf16* __restrict__ Q, const bf16* __restrict__ Kg,
    const bf16* __restrict__ Vt, bf16* __restrict__ O)
{
    const int t    = threadIdx.x;
    const int lane = t & 63, w = t >> 6;      // w = 0..3
    const int quad = lane >> 4, col = lane & 15;
    const int bh   = blockIdx.x & 31;
    const int z    = blockIdx.x >> 5;         // 0..31
    const int qt   = 31 - z;                  // longest-first (LPT packing)
    const int b  = bh >> 4, h = bh & 15;
    const float nslope = -EXP2F(-0.5f * (float)(h + 1)) * LOG2E;

    const bf16* qp  = Q  + (size_t)bh * 2048 * 64;
    const bf16* kp  = Kg + (size_t)bh * 2048 * 64;
    const bf16* vtp = Vt + (size_t)bh * 64 * 2048;   // V^T: [64][2048]

    __shared__ alignas(16) bf16 Kbuf[2][64 * 64];
    __shared__ alignas(16) bf16 Vbuf[2][64 * 64];
    __shared__ alignas(16) bf16 Ps[4 * 16 * 72];
    bf16* Pw = Ps + w * (16 * 72);

    const int q0 = qt * 64;

    bf16x8 qa[2];
#pragma unroll
    for (int ks = 0; ks < 2; ++ks)
        qa[ks] = *(const bf16x8*)(qp + (size_t)(q0 + w * 16 + col) * 64
                                  + ks * 32 + quad * 8);

    float mrow[4], lrow[4], bi[4];
    f32x4 of[4] = {};
    const int gi0 = q0 + w * 16 + quad * 4;
#pragma unroll
    for (int r = 0; r < 4; ++r) {
        mrow[r] = NEG_BIG; lrow[r] = 0.f;
        bi[r] = nslope * (float)(gi0 + r);
    }

    // prologue: stage kv-tile 0 into buffer 0 (512 16B-chunks each)
    {
#pragma unroll
        for (int i = 0; i < 2; ++i) {
            int c = i * 256 + t;
            int row = c >> 3, j8 = (c & 7) ^ (row & 7);
            stage16(kp + (size_t)row * 64 + j8 * 8, Kbuf[0] + (i * 256 + w * 64) * 8);
        }
#pragma unroll
        for (int i = 0; i < 2; ++i) {
            int c = i * 256 + t;
            int d = c >> 3, j8 = (c & 7) ^ (d & 7);
            stage16(vtp + (size_t)d * 2048 + j8 * 8, Vbuf[0] + (i * 256 + w * 64) * 8);
        }
    }
    __syncthreads();

    for (int kvt = 0; kvt <= qt; ++kvt) {
        const int kv0 = kvt * 64;
        const bf16* Kb = Kbuf[kvt & 1];
        const bf16* Vb = Vbuf[kvt & 1];

        // prefetch next tile into the other buffer (async; drained by the
        // end-of-iteration barrier)
        if (kvt < qt) {
            bf16* Kn = Kbuf[(kvt & 1) ^ 1];
            bf16* Vn = Vbuf[(kvt & 1) ^ 1];
            const int nv0 = kv0 + 64;
#pragma unroll
            for (int i = 0; i < 2; ++i) {
                int c = i * 256 + t;
                int row = c >> 3, j8 = (c & 7) ^ (row & 7);
                stage16(kp + (size_t)(nv0 + row) * 64 + j8 * 8, Kn + (i * 256 + w * 64) * 8);
            }
#pragma unroll
            for (int i = 0; i < 2; ++i) {
                int c = i * 256 + t;
                int d = c >> 3, j8 = (c & 7) ^ (d & 7);
                stage16(vtp + (size_t)d * 2048 + nv0 + j8 * 8, Vn + (i * 256 + w * 64) * 8);
            }
        }

        // S = Q K^T  (swizzled K reads: chunk = (quad + 4*ks) ^ (row&7))
        f32x4 sc[4];
#pragma unroll
        for (int nj = 0; nj < 4; ++nj) {
            const int row = nj * 16 + col;
            const bf16* kb = Kb + row * 64;
            const int rx = row & 7;
            bf16x8 k0f = *(const bf16x8*)(kb + (quad ^ rx) * 8);
            bf16x8 k1f = *(const bf16x8*)(kb + ((quad + 4) ^ rx) * 8);
            f32x4 zz = {};
            zz = __builtin_amdgcn_mfma_f32_16x16x32_bf16(qa[0], k0f, zz, 0, 0, 0);
            zz = __builtin_amdgcn_mfma_f32_16x16x32_bf16(qa[1], k1f, zz, 0, 0, 0);
            sc[nj] = zz;
        }

        // softmax (exp2-domain, DPP reduces, hoisted ALiBi)
        const bool diag = (kvt == qt);
        float bj[4];
#pragma unroll
        for (int nj = 0; nj < 4; ++nj)
            bj[nj] = nslope * (float)(kv0 + nj * 16 + col);

#pragma unroll
        for (int r = 0; r < 4; ++r) {
#pragma unroll
            for (int nj = 0; nj < 4; ++nj)
                sc[nj][r] += bi[r] - bj[nj];
            if (diag) {
                const int gi = gi0 + r;
#pragma unroll
                for (int nj = 0; nj < 4; ++nj)
                    if (kv0 + nj * 16 + col > gi) sc[nj][r] = NEG_BIG;
            }
            float mx = sc[0][r];
#pragma unroll
            for (int nj = 1; nj < 4; ++nj) mx = fmaxf(mx, sc[nj][r]);
            mx = red16_max(mx);
            const float mo = mrow[r];
            const float mn = fmaxf(mo, mx);
            const float alpha = EXP2F(mo - mn);
            float rs = 0.f;
#pragma unroll
            for (int nj = 0; nj < 4; ++nj) {
                float p = EXP2F(sc[nj][r] - mn);
                sc[nj][r] = p;
                rs += p;
            }
            rs = red16_sum(rs);
            mrow[r] = mn;
            lrow[r] = lrow[r] * alpha + rs;
#pragma unroll
            for (int jd = 0; jd < 4; ++jd) of[jd][r] *= alpha;
        }

        // P: C/D -> A-operand layout via private per-wave LDS region
        // (wave-private: no barrier; compiler inserts the lgkmcnt)
#pragma unroll
        for (int nj = 0; nj < 4; ++nj)
#pragma unroll
            for (int r = 0; r < 4; ++r)
                Pw[(quad * 4 + r) * 72 + nj * 16 + col] = (bf16)sc[nj][r];

        // O += P V  (swizzled V reads: chunk = (kk*4+quad) ^ (d&7))
#pragma unroll
        for (int kk = 0; kk < 2; ++kk) {
            bf16x8 pa = *(const bf16x8*)(Pw + col * 72 + kk * 32 + quad * 8);
#pragma unroll
            for (int jd = 0; jd < 4; ++jd) {
                const int rd = jd * 16 + col;
                bf16x8 vbf = *(const bf16x8*)(Vb + rd * 64 + (((kk * 4 + quad) ^ (rd & 7)) * 8));
                of[jd] = __builtin_amdgcn_mfma_f32_16x16x32_bf16(pa, vbf, of[jd], 0, 0, 0);
            }
        }

        // ONE barrier: (a) everyone done reading Kb/Vb before next-iter
        // overwrite, (b) vmcnt drain -> prefetched tile visible next iter.
        __syncthreads();
    }

    // normalize + write this q-tile's attn output (bf16) to [B,S,E]
#pragma unroll
    for (int r = 0; r < 4; ++r) {
        const int s = q0 + w * 16 + quad * 4 + r;
        const float inv_l = 1.f / lrow[r];
#pragma unroll
        for (int jd = 0; jd < 4; ++jd) {
            const int e = h * 64 + jd * 16 + col;
            O[((size_t)(b * 2048 + s)) * 1024 + e] = (bf16)(of[jd][r] * inv_l);
        }
    }
}

// ---------------------------------------------------------------------------
// Output projection — now ALL-bf16 (qkv-proven structure): A and Wo-bf16 both
// via stage16 (removes the f32 cvt8 inline-load latency from the K-loop).
// ---------------------------------------------------------------------------
__global__ __launch_bounds__(256) void out_gemm(
    const bf16* __restrict__ A, const bf16* __restrict__ Wb,
    const float* __restrict__ bias, float* __restrict__ out)
{
    __shared__ alignas(16) bf16 As[128 * 32];
    __shared__ alignas(16) bf16 Bs[128 * 32];

    const int t    = threadIdx.x;
    const int lane = t & 63, w = t >> 6;
    const int quad = lane >> 4, col = lane & 15;
    const int n0 = blockIdx.x * 128;
    const int m0 = blockIdx.y * 128;
    const int K  = 1024;
    const int wm = (w >> 1) * 64, wn = (w & 1) * 64;
    f32x4 acc[4][4] = {};

    for (int k0 = 0; k0 < K; k0 += 32) {
        __syncthreads();
#pragma unroll
        for (int i = 0; i < 2; ++i) {
            int c = i * 256 + t;
            stage16(A + (size_t)(m0 + (c >> 2)) * K + k0 + (c & 3) * 8,
                    As + (i * 256 + w * 64) * 8);
        }
#pragma unroll
        for (int i = 0; i < 2; ++i) {
            int c = i * 256 + t;
            stage16(Wb + (size_t)(n0 + (c >> 2)) * K + k0 + (c & 3) * 8,
                    Bs + (i * 256 + w * 64) * 8);
        }
        __syncthreads();

        bf16x8 a[4], b[4];
#pragma unroll
        for (int i = 0; i < 4; ++i)
            a[i] = *(const bf16x8*)(As + (wm + i * 16 + col) * 32 + quad * 8);
#pragma unroll
        for (int j = 0; j < 4; ++j)
            b[j] = *(const bf16x8*)(Bs + (wn + j * 16 + col) * 32 + quad * 8);
#pragma unroll
        for (int i = 0; i < 4; ++i)
#pragma unroll
            for (int j = 0; j < 4; ++j)
                acc[i][j] = __builtin_amdgcn_mfma_f32_16x16x32_bf16(a[i], b[j], acc[i][j], 0, 0, 0);
    }

#pragma unroll
    for (int i = 0; i < 4; ++i) {
        const int mbase = m0 + wm + i * 16 + quad * 4;
#pragma unroll
        for (int j = 0; j < 4; ++j) {
            const int n = n0 + wn + j * 16 + col;
            const float bb = bias[n];
#pragma unroll
            for (int r = 0; r < 4; ++r)
                out[(size_t)(mbase + r) * 1024 + n] = acc[i][j][r] + bb;
        }
    }
}

extern "C" void kernel_launch(void* const* d_in, const int* in_sizes, int n_in,
                              void* d_out, int out_size, void* d_ws, size_t ws_size,
                              hipStream_t stream) {
    const float* x  = (const float*)d_in[0];
    const float* Wq = (const float*)d_in[1];
    const float* bq = (const float*)d_in[2];
    const float* Wk = (const float*)d_in[3];
    const float* bk = (const float*)d_in[4];
    const float* Wv = (const float*)d_in[5];
    const float* bv = (const float*)d_in[6];
    const float* Wo = (const float*)d_in[7];
    const float* bo = (const float*)d_in[8];
    float* out = (float*)d_out;

    // ws (32 MB, proven): [xb | q | k | v^T] bf16; attn output aliases xb.
    // After attn, qws is dead -> reused for Wo-bf16 (stream order serializes
    // conv_wo after attn's Q reads).
    bf16* xb  = (bf16*)d_ws;
    bf16* qws = xb  + 4194304;
    bf16* kws = qws + 4194304;
    bf16* vws = kws + 4194304;
    bf16* aws = xb;
    bf16* wob = qws;

    // d_out scratch: bf16 Wq|Wk|Wv (6 MB); dead before out_gemm writes.
    bf16* wb = (bf16*)d_out;

    conv_all<<<dim3(3584), 256, 0, stream>>>(x, Wq, Wk, Wv, xb, wb);
    qkv_gemm<<<dim3(32, 24), 256, 0, stream>>>(xb, wb, bq, bk, bv, qws, kws, vws);
    attn_kernel<<<dim3(1024), 256, 0, stream>>>(qws, kws, vws, aws);
    conv_wo<<<dim3(512), 256, 0, stream>>>(Wo, wob);
    out_gemm<<<dim3(8, 32), 256, 0, stream>>>(aws, wob, bo, out);
}

// Round 13
// 195.344 us; speedup vs baseline: 1.2886x; 1.0025x over previous
//
#include <hip/hip_runtime.h>
#include <hip/hip_bf16.h>

typedef __bf16 bf16;
typedef __bf16 bf16x4 __attribute__((ext_vector_type(4)));
typedef __bf16 bf16x8 __attribute__((ext_vector_type(8)));
typedef float  f32x4  __attribute__((ext_vector_type(4)));

#define NEG_BIG (-1e30f)
#define LOG2E 1.44269504088896340736f

#define AS1(p) ((const __attribute__((address_space(1))) void*)(p))
#define AS3(p) ((__attribute__((address_space(3))) void*)(p))

// async global->LDS, 16B/lane; dest = wave-uniform base + lane*16 (m104/m108)
__device__ __forceinline__ void stage16(const void* g, void* lds_uniform_base) {
    __builtin_amdgcn_global_load_lds(AS1(g), AS3(lds_uniform_base), 16, 0, 0);
}

__device__ __forceinline__ bf16x8 cvt8(const float* __restrict__ p) {
    bf16x8 r;
#pragma unroll
    for (int i = 0; i < 8; ++i) r[i] = (bf16)p[i];
    return r;
}

// ---- DPP butterfly reduce over 16 consecutive lanes (pure VALU, no LDS) ----
template <int CTRL>
__device__ __forceinline__ float dpp_max_step(float x) {
    int v = __builtin_bit_cast(int, x);
    int s = __builtin_amdgcn_update_dpp(v, v, CTRL, 0xF, 0xF, true);
    return fmaxf(x, __builtin_bit_cast(float, s));
}
template <int CTRL>
__device__ __forceinline__ float dpp_add_step(float x) {
    int v = __builtin_bit_cast(int, x);
    int s = __builtin_amdgcn_update_dpp(v, v, CTRL, 0xF, 0xF, true);
    return x + __builtin_bit_cast(float, s);
}
__device__ __forceinline__ float red16_max(float x) {
    x = dpp_max_step<0xB1>(x);
    x = dpp_max_step<0x4E>(x);
    x = dpp_max_step<0x141>(x);
    x = dpp_max_step<0x140>(x);
    return x;
}
__device__ __forceinline__ float red16_sum(float x) {
    x = dpp_add_step<0xB1>(x);
    x = dpp_add_step<0x4E>(x);
    x = dpp_add_step<0x141>(x);
    x = dpp_add_step<0x140>(x);
    return x;
}

#if __has_builtin(__builtin_amdgcn_exp2f)
#define EXP2F(x) __builtin_amdgcn_exp2f(x)
#else
#define EXP2F(x) exp2f(x)
#endif

// ---------------------------------------------------------------------------
// f32->bf16: x -> xb (ws), Wq/Wk/Wv -> wb (d_out scratch). (R7-proven.)
// ---------------------------------------------------------------------------
__global__ __launch_bounds__(256) void conv_all(
    const float* __restrict__ x,  const float* __restrict__ wq,
    const float* __restrict__ wk, const float* __restrict__ wv,
    bf16* __restrict__ xb, bf16* __restrict__ wb)
{
    const int blk = blockIdx.x;
    const float* src; bf16* dst; size_t off;
    if (blk < 2048)      { src = x;  dst = xb;           off = (size_t)blk * 2048; }
    else if (blk < 2560) { src = wq; dst = wb;           off = (size_t)(blk - 2048) * 2048; }
    else if (blk < 3072) { src = wk; dst = wb + 1048576; off = (size_t)(blk - 2560) * 2048; }
    else                 { src = wv; dst = wb + 2097152; off = (size_t)(blk - 3072) * 2048; }
    const size_t i = off + (size_t)threadIdx.x * 8;
    *(bf16x8*)(dst + i) = cvt8(src + i);
}

// ---------------------------------------------------------------------------
// Wo f32 -> bf16 into qws (dead after attn; stream order serializes). 4 MB read.
// ---------------------------------------------------------------------------
__global__ __launch_bounds__(256) void conv_wo(
    const float* __restrict__ w, bf16* __restrict__ wb)
{
    const size_t i = ((size_t)blockIdx.x * 256 + threadIdx.x) * 8;
    *(bf16x8*)(wb + i) = cvt8(w + i);
}

// ---------------------------------------------------------------------------
// Fused QKV projection, all-bf16 (R7-proven core). y = xb @ Wb.T + b.
// Q is scaled by 0.125*log2e (exp2-domain softmax). V is written TRANSPOSED:
// V^T[bh][64][2048] so attn can stage it with global_load_lds (no transpose).
// Grid swapped to (mt, nt): consecutive blocks share the B panel (L2 heuristic).
// ---------------------------------------------------------------------------
__global__ __launch_bounds__(256) void qkv_gemm(
    const bf16* __restrict__ Xb, const bf16* __restrict__ Wb,
    const float* __restrict__ bq, const float* __restrict__ bk, const float* __restrict__ bv,
    bf16* __restrict__ qo, bf16* __restrict__ ko, bf16* __restrict__ vo)
{
    __shared__ alignas(16) bf16 As[128 * 32];
    __shared__ alignas(16) bf16 Bs[128 * 32];

    const int t    = threadIdx.x;
    const int lane = t & 63, w = t >> 6;
    const int quad = lane >> 4, col = lane & 15;
    const int mt = blockIdx.x;            // 0..31
    const int nt = blockIdx.y;            // 0..23
    const int region = nt >> 3;           // 0=q 1=k 2=v
    const int n0 = (nt & 7) * 128;
    const int m0 = mt * 128;
    const int K  = 1024;

    const bf16*  W    = Wb + (size_t)region * 1048576;
    const float* bias = region == 0 ? bq : (region == 1 ? bk : bv);

    const int wm = (w >> 1) * 64, wn = (w & 1) * 64;
    f32x4 acc[4][4] = {};

    for (int k0 = 0; k0 < K; k0 += 32) {
        __syncthreads();
#pragma unroll
        for (int i = 0; i < 2; ++i) {
            int c = i * 256 + t;
            stage16(Xb + (size_t)(m0 + (c >> 2)) * K + k0 + (c & 3) * 8,
                    As + (i * 256 + w * 64) * 8);
        }
#pragma unroll
        for (int i = 0; i < 2; ++i) {
            int c = i * 256 + t;
            stage16(W + (size_t)(n0 + (c >> 2)) * K + k0 + (c & 3) * 8,
                    Bs + (i * 256 + w * 64) * 8);
        }
        __syncthreads();

        bf16x8 a[4], b[4];
#pragma unroll
        for (int i = 0; i < 4; ++i)
            a[i] = *(const bf16x8*)(As + (wm + i * 16 + col) * 32 + quad * 8);
#pragma unroll
        for (int j = 0; j < 4; ++j)
            b[j] = *(const bf16x8*)(Bs + (wn + j * 16 + col) * 32 + quad * 8);
#pragma unroll
        for (int i = 0; i < 4; ++i)
#pragma unroll
            for (int j = 0; j < 4; ++j)
                acc[i][j] = __builtin_amdgcn_mfma_f32_16x16x32_bf16(a[i], b[j], acc[i][j], 0, 0, 0);
    }

    if (region == 2) {
        // V^T epilogue: rows d = n&63, cols s (contiguous in r) -> packed 8B stores
#pragma unroll
        for (int i = 0; i < 4; ++i) {
            const int mbase = m0 + wm + i * 16 + quad * 4;
            const int b_ = mbase >> 11, s = mbase & 2047;
#pragma unroll
            for (int j = 0; j < 4; ++j) {
                const int n = n0 + wn + j * 16 + col;
                const float bb = bias[n];
                const int h = n >> 6, d = n & 63;
                bf16x4 pk;
#pragma unroll
                for (int r = 0; r < 4; ++r) pk[r] = (bf16)(acc[i][j][r] + bb);
                *(bf16x4*)(vo + ((size_t)(b_ * 16 + h) * 64 + d) * 2048 + s) = pk;
            }
        }
    } else {
        bf16* out = region == 0 ? qo : ko;
        const float scale = region == 0 ? (0.125f * LOG2E) : 1.0f;
#pragma unroll
        for (int i = 0; i < 4; ++i) {
            const int mbase = m0 + wm + i * 16 + quad * 4;
#pragma unroll
            for (int j = 0; j < 4; ++j) {
                const int n = n0 + wn + j * 16 + col;
                const float bb = bias[n];
                const int h = n >> 6, d = n & 63;
#pragma unroll
                for (int r = 0; r < 4; ++r) {
                    const int m  = mbase + r;
                    const int b_ = m >> 11, s = m & 2047;
                    out[(((size_t)(b_ * 16 + h)) * 2048 + s) * 64 + d] =
                        (bf16)((acc[i][j][r] + bb) * scale);
                }
            }
        }
    }
}

// ---------------------------------------------------------------------------
// Flash attention — R12-exact EXCEPT one change: P region stride 72 -> 64
// with XOR chunk-swizzle (write P[prow][kv] at prow*64 + ((kv>>3)^(prow&7))*8
// + (kv&7); read chunk (kk*4+quad)^(col&7)). Bijective per row; matches the
// MFMA A-fragment chunk layout. LDS 41984 -> 40960 B = EXACTLY 4 blocks/CU
// (163840/40960), up from 3 — the occupancy limiter was LDS by 4KB.
// Everything else identical to the proven 54us kernel.
// ---------------------------------------------------------------------------
__global__ __launch_bounds__(256, 4) void attn_kernel(
    const bf16* __restrict__ Q, const bf16* __restrict__ Kg,
    const bf16* __restrict__ Vt, bf16* __restrict__ O)
{
    const int t    = threadIdx.x;
    const int lane = t & 63, w = t >> 6;      // w = 0..3
    const int quad = lane >> 4, col = lane & 15;
    const int bh   = blockIdx.x & 31;
    const int z    = blockIdx.x >> 5;         // 0..31
    const int qt   = 31 - z;                  // longest-first (LPT packing)
    const int b  = bh >> 4, h = bh & 15;
    const float nslope = -EXP2F(-0.5f * (float)(h + 1)) * LOG2E;

    const bf16* qp  = Q  + (size_t)bh * 2048 * 64;
    const bf16* kp  = Kg + (size_t)bh * 2048 * 64;
    const bf16* vtp = Vt + (size_t)bh * 64 * 2048;   // V^T: [64][2048]

    __shared__ alignas(16) bf16 Kbuf[2][64 * 64];
    __shared__ alignas(16) bf16 Vbuf[2][64 * 64];
    __shared__ alignas(16) bf16 Ps[4 * 16 * 64];     // XOR-swizzled, no pad
    bf16* Pw = Ps + w * (16 * 64);

    const int q0 = qt * 64;

    bf16x8 qa[2];
#pragma unroll
    for (int ks = 0; ks < 2; ++ks)
        qa[ks] = *(const bf16x8*)(qp + (size_t)(q0 + w * 16 + col) * 64
                                  + ks * 32 + quad * 8);

    float mrow[4], lrow[4], bi[4];
    f32x4 of[4] = {};
    const int gi0 = q0 + w * 16 + quad * 4;
#pragma unroll
    for (int r = 0; r < 4; ++r) {
        mrow[r] = NEG_BIG; lrow[r] = 0.f;
        bi[r] = nslope * (float)(gi0 + r);
    }

    // prologue: stage kv-tile 0 into buffer 0 (512 16B-chunks each)
    {
#pragma unroll
        for (int i = 0; i < 2; ++i) {
            int c = i * 256 + t;
            int row = c >> 3, j8 = (c & 7) ^ (row & 7);
            stage16(kp + (size_t)row * 64 + j8 * 8, Kbuf[0] + (i * 256 + w * 64) * 8);
        }
#pragma unroll
        for (int i = 0; i < 2; ++i) {
            int c = i * 256 + t;
            int d = c >> 3, j8 = (c & 7) ^ (d & 7);
            stage16(vtp + (size_t)d * 2048 + j8 * 8, Vbuf[0] + (i * 256 + w * 64) * 8);
        }
    }
    __syncthreads();

    for (int kvt = 0; kvt <= qt; ++kvt) {
        const int kv0 = kvt * 64;
        const bf16* Kb = Kbuf[kvt & 1];
        const bf16* Vb = Vbuf[kvt & 1];

        // prefetch next tile into the other buffer (async; drained by the
        // end-of-iteration barrier)
        if (kvt < qt) {
            bf16* Kn = Kbuf[(kvt & 1) ^ 1];
            bf16* Vn = Vbuf[(kvt & 1) ^ 1];
            const int nv0 = kv0 + 64;
#pragma unroll
            for (int i = 0; i < 2; ++i) {
                int c = i * 256 + t;
                int row = c >> 3, j8 = (c & 7) ^ (row & 7);
                stage16(kp + (size_t)(nv0 + row) * 64 + j8 * 8, Kn + (i * 256 + w * 64) * 8);
            }
#pragma unroll
            for (int i = 0; i < 2; ++i) {
                int c = i * 256 + t;
                int d = c >> 3, j8 = (c & 7) ^ (d & 7);
                stage16(vtp + (size_t)d * 2048 + nv0 + j8 * 8, Vn + (i * 256 + w * 64) * 8);
            }
        }

        // S = Q K^T  (swizzled K reads: chunk = (quad + 4*ks) ^ (row&7))
        f32x4 sc[4];
#pragma unroll
        for (int nj = 0; nj < 4; ++nj) {
            const int row = nj * 16 + col;
            const bf16* kb = Kb + row * 64;
            const int rx = row & 7;
            bf16x8 k0f = *(const bf16x8*)(kb + (quad ^ rx) * 8);
            bf16x8 k1f = *(const bf16x8*)(kb + ((quad + 4) ^ rx) * 8);
            f32x4 zz = {};
            zz = __builtin_amdgcn_mfma_f32_16x16x32_bf16(qa[0], k0f, zz, 0, 0, 0);
            zz = __builtin_amdgcn_mfma_f32_16x16x32_bf16(qa[1], k1f, zz, 0, 0, 0);
            sc[nj] = zz;
        }

        // softmax (exp2-domain, DPP reduces, hoisted ALiBi)
        const bool diag = (kvt == qt);
        float bj[4];
#pragma unroll
        for (int nj = 0; nj < 4; ++nj)
            bj[nj] = nslope * (float)(kv0 + nj * 16 + col);

#pragma unroll
        for (int r = 0; r < 4; ++r) {
#pragma unroll
            for (int nj = 0; nj < 4; ++nj)
                sc[nj][r] += bi[r] - bj[nj];
            if (diag) {
                const int gi = gi0 + r;
#pragma unroll
                for (int nj = 0; nj < 4; ++nj)
                    if (kv0 + nj * 16 + col > gi) sc[nj][r] = NEG_BIG;
            }
            float mx = sc[0][r];
#pragma unroll
            for (int nj = 1; nj < 4; ++nj) mx = fmaxf(mx, sc[nj][r]);
            mx = red16_max(mx);
            const float mo = mrow[r];
            const float mn = fmaxf(mo, mx);
            const float alpha = EXP2F(mo - mn);
            float rs = 0.f;
#pragma unroll
            for (int nj = 0; nj < 4; ++nj) {
                float p = EXP2F(sc[nj][r] - mn);
                sc[nj][r] = p;
                rs += p;
            }
            rs = red16_sum(rs);
            mrow[r] = mn;
            lrow[r] = lrow[r] * alpha + rs;
#pragma unroll
            for (int jd = 0; jd < 4; ++jd) of[jd][r] *= alpha;
        }

        // P: C/D -> A-operand layout, XOR-swizzled per-wave region (no pad).
        // P[prow][kv] at prow*64 + ((kv>>3)^(prow&7))*8 + (kv&7); wave-private.
#pragma unroll
        for (int nj = 0; nj < 4; ++nj)
#pragma unroll
            for (int r = 0; r < 4; ++r) {
                const int prow = quad * 4 + r;
                Pw[prow * 64 + (((nj * 2 + (col >> 3)) ^ (prow & 7)) * 8) + (col & 7)]
                    = (bf16)sc[nj][r];
            }

        // O += P V  (swizzled P reads: chunk = (kk*4+quad) ^ (col&7);
        //            swizzled V reads: chunk = (kk*4+quad) ^ (d&7))
#pragma unroll
        for (int kk = 0; kk < 2; ++kk) {
            bf16x8 pa = *(const bf16x8*)(Pw + col * 64 + (((kk * 4 + quad) ^ (col & 7)) * 8));
#pragma unroll
            for (int jd = 0; jd < 4; ++jd) {
                const int rd = jd * 16 + col;
                bf16x8 vbf = *(const bf16x8*)(Vb + rd * 64 + (((kk * 4 + quad) ^ (rd & 7)) * 8));
                of[jd] = __builtin_amdgcn_mfma_f32_16x16x32_bf16(pa, vbf, of[jd], 0, 0, 0);
            }
        }

        // ONE barrier: (a) everyone done reading Kb/Vb before next-iter
        // overwrite, (b) vmcnt drain -> prefetched tile visible next iter.
        __syncthreads();
    }

    // normalize + write this q-tile's attn output (bf16) to [B,S,E]
#pragma unroll
    for (int r = 0; r < 4; ++r) {
        const int s = q0 + w * 16 + quad * 4 + r;
        const float inv_l = 1.f / lrow[r];
#pragma unroll
        for (int jd = 0; jd < 4; ++jd) {
            const int e = h * 64 + jd * 16 + col;
            O[((size_t)(b * 2048 + s)) * 1024 + e] = (bf16)(of[jd][r] * inv_l);
        }
    }
}

// ---------------------------------------------------------------------------
// Output projection — ALL-bf16 (qkv-proven structure): A and Wo-bf16 both
// via stage16 (removes the f32 cvt8 inline-load latency from the K-loop).
// ---------------------------------------------------------------------------
__global__ __launch_bounds__(256) void out_gemm(
    const bf16* __restrict__ A, const bf16* __restrict__ Wb,
    const float* __restrict__ bias, float* __restrict__ out)
{
    __shared__ alignas(16) bf16 As[128 * 32];
    __shared__ alignas(16) bf16 Bs[128 * 32];

    const int t    = threadIdx.x;
    const int lane = t & 63, w = t >> 6;
    const int quad = lane >> 4, col = lane & 15;
    const int n0 = blockIdx.x * 128;
    const int m0 = blockIdx.y * 128;
    const int K  = 1024;
    const int wm = (w >> 1) * 64, wn = (w & 1) * 64;
    f32x4 acc[4][4] = {};

    for (int k0 = 0; k0 < K; k0 += 32) {
        __syncthreads();
#pragma unroll
        for (int i = 0; i < 2; ++i) {
            int c = i * 256 + t;
            stage16(A + (size_t)(m0 + (c >> 2)) * K + k0 + (c & 3) * 8,
                    As + (i * 256 + w * 64) * 8);
        }
#pragma unroll
        for (int i = 0; i < 2; ++i) {
            int c = i * 256 + t;
            stage16(Wb + (size_t)(n0 + (c >> 2)) * K + k0 + (c & 3) * 8,
                    Bs + (i * 256 + w * 64) * 8);
        }
        __syncthreads();

        bf16x8 a[4], b[4];
#pragma unroll
        for (int i = 0; i < 4; ++i)
            a[i] = *(const bf16x8*)(As + (wm + i * 16 + col) * 32 + quad * 8);
#pragma unroll
        for (int j = 0; j < 4; ++j)
            b[j] = *(const bf16x8*)(Bs + (wn + j * 16 + col) * 32 + quad * 8);
#pragma unroll
        for (int i = 0; i < 4; ++i)
#pragma unroll
            for (int j = 0; j < 4; ++j)
                acc[i][j] = __builtin_amdgcn_mfma_f32_16x16x32_bf16(a[i], b[j], acc[i][j], 0, 0, 0);
    }

#pragma unroll
    for (int i = 0; i < 4; ++i) {
        const int mbase = m0 + wm + i * 16 + quad * 4;
#pragma unroll
        for (int j = 0; j < 4; ++j) {
            const int n = n0 + wn + j * 16 + col;
            const float bb = bias[n];
#pragma unroll
            for (int r = 0; r < 4; ++r)
                out[(size_t)(mbase + r) * 1024 + n] = acc[i][j][r] + bb;
        }
    }
}

extern "C" void kernel_launch(void* const* d_in, const int* in_sizes, int n_in,
                              void* d_out, int out_size, void* d_ws, size_t ws_size,
                              hipStream_t stream) {
    const float* x  = (const float*)d_in[0];
    const float* Wq = (const float*)d_in[1];
    const float* bq = (const float*)d_in[2];
    const float* Wk = (const float*)d_in[3];
    const float* bk = (const float*)d_in[4];
    const float* Wv = (const float*)d_in[5];
    const float* bv = (const float*)d_in[6];
    const float* Wo = (const float*)d_in[7];
    const float* bo = (const float*)d_in[8];
    float* out = (float*)d_out;

    // ws (32 MB, proven): [xb | q | k | v^T] bf16; attn output aliases xb.
    // After attn, qws is dead -> reused for Wo-bf16 (stream order serializes
    // conv_wo after attn's Q reads).
    bf16* xb  = (bf16*)d_ws;
    bf16* qws = xb  + 4194304;
    bf16* kws = qws + 4194304;
    bf16* vws = kws + 4194304;
    bf16* aws = xb;
    bf16* wob = qws;

    // d_out scratch: bf16 Wq|Wk|Wv (6 MB); dead before out_gemm writes.
    bf16* wb = (bf16*)d_out;

    conv_all<<<dim3(3584), 256, 0, stream>>>(x, Wq, Wk, Wv, xb, wb);
    qkv_gemm<<<dim3(32, 24), 256, 0, stream>>>(xb, wb, bq, bk, bv, qws, kws, vws);
    attn_kernel<<<dim3(1024), 256, 0, stream>>>(qws, kws, vws, aws);
    conv_wo<<<dim3(512), 256, 0, stream>>>(Wo, wob);
    out_gemm<<<dim3(8, 32), 256, 0, stream>>>(aws, wob, bo, out);
}